// Round 6
// baseline (296.124 us; speedup 1.0000x reference)
//
#include <hip/hip_runtime.h>
#include <hip/hip_bf16.h>

// Problem dims (fixed by reference setup_inputs)
#define NQ 8
#define NK 1024
#define ND 64
#define NH 1024
#define NB 8
#define NT 8192

typedef float vfloat4 __attribute__((ext_vector_type(4)));

__device__ __forceinline__ unsigned bf16_rne(float f) {
    unsigned u = __float_as_uint(f);
    return (u + 0x7fffu + ((u >> 16) & 1u)) >> 16;
}

// ------------- Kernel 1: build projected codebook, tiled bf16 layout -------
// Pt[hg][q][k] = uint2 packing bf16 of
//   P[q,k,h] = bias[q][h] + sum_d codebooks[q][k][d]*W[q][h][d],  h = hg*4+{0..3}
// Layout is hg-major so the gather kernel stages one contiguous 64 KB slice.
// Block = (q, k-range 256, hg-block 16): thread owns k; cb row in 64 VGPRs;
// W rows broadcast from LDS; stores coalesced along k.
__global__ __launch_bounds__(256, 4) void build_Pt(const float* __restrict__ cb,
                                                   const float* __restrict__ W,
                                                   const float* __restrict__ bias,
                                                   uint2* __restrict__ Pt) {
    int q   = blockIdx.x >> 6;         // 64 blocks per q
    int kr  = (blockIdx.x >> 4) & 3;   // 4 k-ranges
    int hgb = blockIdx.x & 15;         // 16 hg-blocks (64 h each)
    int tid = threadIdx.x;
    int k   = kr * 256 + tid;
    int h0  = hgb * 64;

    __shared__ float Wl[64][ND];  // 16 KB: W rows h0..h0+63
    __shared__ float bl[64];
    const float4* wsrc = (const float4*)(W + ((size_t)q * NH + h0) * ND);
    float4* wdst = (float4*)&Wl[0][0];
    for (int i = tid; i < 64 * ND / 4; i += 256) wdst[i] = wsrc[i];
    if (tid < 64) bl[tid] = bias[q * NH + h0 + tid];
    __syncthreads();

    float4 c4[ND / 4];  // this thread's codebook row (64 f32)
    const float4* csrc = (const float4*)(cb + ((size_t)q * NK + k) * ND);
#pragma unroll
    for (int i = 0; i < ND / 4; ++i) c4[i] = csrc[i];

    for (int hg = 0; hg < 16; ++hg) {
        float acc[4];
#pragma unroll
        for (int hh = 0; hh < 4; ++hh) {
            int r = hg * 4 + hh;
            float a = bl[r];
            const float4* wrow = (const float4*)&Wl[r][0];  // broadcast read
#pragma unroll
            for (int i = 0; i < ND / 4; ++i) {
                float4 w4 = wrow[i];
                a += c4[i].x * w4.x + c4[i].y * w4.y + c4[i].z * w4.z + c4[i].w * w4.w;
            }
            acc[hh] = a;
        }
        uint2 pk;
        pk.x = bf16_rne(acc[0]) | (bf16_rne(acc[1]) << 16);
        pk.y = bf16_rne(acc[2]) | (bf16_rne(acc[3]) << 16);
        int hgg = hgb * 16 + hg;
        Pt[((size_t)hgg * NQ + q) * NK + k] = pk;  // coalesced along k
    }
}

// ------------- Kernel 2: LDS-staged gather-sum, register h, x4 stores ------
// out[b,h,t] = sum_q P[q, codes[q,b,t], h]
// Block = (hg, b): stages Pt slice [8 q][1024 k][4 h] = 64 KB into LDS once,
// then streams t: thread owns 4 consecutive t; per (t,q) one ds_read_b64
// (4 bf16 h-values) accumulated into 16 registers; output written as
// nontemporal dwordx4 (no LDS transpose needed - h is register-resident).
// blockIdx&7 = b pins each batch's codes slice to one XCD's L2.
__global__ __launch_bounds__(512, 4) void gather_sum(const int* __restrict__ codes,
                                                     const uint2* __restrict__ Pt,
                                                     float* __restrict__ out) {
    int b   = blockIdx.x & 7;
    int hg  = blockIdx.x >> 3;   // 0..255
    int tid = threadIdx.x;

    __shared__ uint2 Pl[NQ * NK];  // 64 KB
    const uint4* src = (const uint4*)(Pt + (size_t)hg * NQ * NK);
    uint4* dst = (uint4*)Pl;
#pragma unroll
    for (int i = 0; i < 8; ++i) dst[tid + i * 512] = src[tid + i * 512];
    __syncthreads();

    int h0 = hg * 4;
    for (int j = 0; j < 4; ++j) {
        int t0 = j * 2048 + tid * 4;
        float acc[4][4];  // [tt][hh]
#pragma unroll
        for (int tt = 0; tt < 4; ++tt)
#pragma unroll
            for (int hh = 0; hh < 4; ++hh) acc[tt][hh] = 0.f;

#pragma unroll
        for (int q = 0; q < NQ; ++q) {
            int4 cc = *(const int4*)(codes + ((size_t)q * NB + b) * NT + t0);
#pragma unroll
            for (int tt = 0; tt < 4; ++tt) {
                int c = (tt == 0) ? cc.x : (tt == 1) ? cc.y : (tt == 2) ? cc.z : cc.w;
                uint2 v = Pl[q * NK + c];
                acc[tt][0] += __uint_as_float(v.x << 16);
                acc[tt][1] += __uint_as_float(v.x & 0xffff0000u);
                acc[tt][2] += __uint_as_float(v.y << 16);
                acc[tt][3] += __uint_as_float(v.y & 0xffff0000u);
            }
        }
#pragma unroll
        for (int hh = 0; hh < 4; ++hh) {
            vfloat4 o;
            o.x = acc[0][hh]; o.y = acc[1][hh]; o.z = acc[2][hh]; o.w = acc[3][hh];
            vfloat4* dstp = (vfloat4*)(out + ((size_t)b * NH + (h0 + hh)) * NT + t0);
            __builtin_nontemporal_store(o, dstp);
        }
    }
}

extern "C" void kernel_launch(void* const* d_in, const int* in_sizes, int n_in,
                              void* d_out, int out_size, void* d_ws, size_t ws_size,
                              hipStream_t stream) {
    const int*   codes = (const int*)d_in[0];    // [Q,B,T] int32
    const float* cb    = (const float*)d_in[1];  // [Q,K,D] f32
    const float* W     = (const float*)d_in[2];  // [Q,H,D] f32
    const float* bias  = (const float*)d_in[3];  // [Q,H] f32
    float*       out   = (float*)d_out;          // [B,H,T] f32
    uint2*       Pt    = (uint2*)d_ws;           // [256 hg][Q][K] uint2 = 16 MB

    build_Pt<<<NQ * 4 * 16, 256, 0, stream>>>(cb, W, bias, Pt);
    gather_sum<<<256 * NB, 512, 0, stream>>>(codes, Pt, out);
}

// Round 7
// 101.556 us; speedup vs baseline: 2.9159x; 2.9159x over previous
//
#include <hip/hip_runtime.h>
#include <hip/hip_bf16.h>

// Problem dims (fixed by reference setup_inputs)
#define NQ 8
#define NK 1024
#define ND 64
#define NH 1024
#define NB 8
#define NT 8192

typedef float vfloat4 __attribute__((ext_vector_type(4)));

__device__ __forceinline__ unsigned bf16_rne(float f) {
    unsigned u = __float_as_uint(f);
    return (u + 0x7fffu + ((u >> 16) & 1u)) >> 16;
}

// ------------- Kernel 1: build projected codebook, tiled bf16 layout -------
// Pt[hg][q][k] = uint2 packing bf16 of
//   P[q,k,h] = bias[q][h] + sum_d codebooks[q][k][d]*W[q][h][d],  h = hg*4+{0..3}
// Thread owns k; codebook row (64 f32) lives in VGPRs. NO min-occupancy
// clamp: R6's __launch_bounds__(256,4) capped VGPRs at 64 and spilled c4 to
// scratch (470 MB fetch, 247 us). Registers > occupancy for this kernel.
__global__ __launch_bounds__(256) void build_Pt(const float* __restrict__ cb,
                                                const float* __restrict__ W,
                                                const float* __restrict__ bias,
                                                uint2* __restrict__ Pt) {
    int q   = blockIdx.x >> 6;         // 64 blocks per q
    int kr  = (blockIdx.x >> 4) & 3;   // 4 k-ranges
    int hgb = blockIdx.x & 15;         // 16 hg-blocks (64 h each)
    int tid = threadIdx.x;
    int k   = kr * 256 + tid;
    int h0  = hgb * 64;

    __shared__ float Wl[64][ND];  // 16 KB: W rows h0..h0+63
    __shared__ float bl[64];
    const float4* wsrc = (const float4*)(W + ((size_t)q * NH + h0) * ND);
    float4* wdst = (float4*)&Wl[0][0];
    for (int i = tid; i < 64 * ND / 4; i += 256) wdst[i] = wsrc[i];
    if (tid < 64) bl[tid] = bias[q * NH + h0 + tid];
    __syncthreads();

    float4 c4[ND / 4];  // this thread's codebook row (64 f32, 64 VGPRs)
    const float4* csrc = (const float4*)(cb + ((size_t)q * NK + k) * ND);
#pragma unroll
    for (int i = 0; i < ND / 4; ++i) c4[i] = csrc[i];

    for (int hg = 0; hg < 16; ++hg) {
        float acc[4];
#pragma unroll
        for (int hh = 0; hh < 4; ++hh) {
            int r = hg * 4 + hh;
            float a = bl[r];
            const float4* wrow = (const float4*)&Wl[r][0];  // broadcast read
#pragma unroll
            for (int i = 0; i < ND / 4; ++i) {
                float4 w4 = wrow[i];
                a += c4[i].x * w4.x + c4[i].y * w4.y + c4[i].z * w4.z + c4[i].w * w4.w;
            }
            acc[hh] = a;
        }
        uint2 pk;
        pk.x = bf16_rne(acc[0]) | (bf16_rne(acc[1]) << 16);
        pk.y = bf16_rne(acc[2]) | (bf16_rne(acc[3]) << 16);
        int hgg = hgb * 16 + hg;
        Pt[((size_t)hgg * NQ + q) * NK + k] = pk;  // coalesced along k
    }
}

// ------------- Kernel 2: LDS-staged gather-sum, register h, x4 stores ------
// out[b,h,t] = sum_q P[q, codes[q,b,t], h]
// Block = (hg, b): stages Pt slice [8 q][1024 k][4 h] = 64 KB into LDS once,
// then streams t: thread owns 4 consecutive t; per (t,q) one ds_read_b64
// (4 bf16 h-values) accumulated into 16 registers; output written as
// nontemporal dwordx4 (no LDS transpose needed - h is register-resident).
// blockIdx&7 = b pins each batch's codes slice to one XCD's L2.
__global__ __launch_bounds__(512, 4) void gather_sum(const int* __restrict__ codes,
                                                     const uint2* __restrict__ Pt,
                                                     float* __restrict__ out) {
    int b   = blockIdx.x & 7;
    int hg  = blockIdx.x >> 3;   // 0..255
    int tid = threadIdx.x;

    __shared__ uint2 Pl[NQ * NK];  // 64 KB
    const uint4* src = (const uint4*)(Pt + (size_t)hg * NQ * NK);
    uint4* dst = (uint4*)Pl;
#pragma unroll
    for (int i = 0; i < 8; ++i) dst[tid + i * 512] = src[tid + i * 512];
    __syncthreads();

    int h0 = hg * 4;
    for (int j = 0; j < 4; ++j) {
        int t0 = j * 2048 + tid * 4;
        float acc[4][4];  // [tt][hh]
#pragma unroll
        for (int tt = 0; tt < 4; ++tt)
#pragma unroll
            for (int hh = 0; hh < 4; ++hh) acc[tt][hh] = 0.f;

#pragma unroll
        for (int q = 0; q < NQ; ++q) {
            int4 cc = *(const int4*)(codes + ((size_t)q * NB + b) * NT + t0);
#pragma unroll
            for (int tt = 0; tt < 4; ++tt) {
                int c = (tt == 0) ? cc.x : (tt == 1) ? cc.y : (tt == 2) ? cc.z : cc.w;
                uint2 v = Pl[q * NK + c];
                acc[tt][0] += __uint_as_float(v.x << 16);
                acc[tt][1] += __uint_as_float(v.x & 0xffff0000u);
                acc[tt][2] += __uint_as_float(v.y << 16);
                acc[tt][3] += __uint_as_float(v.y & 0xffff0000u);
            }
        }
#pragma unroll
        for (int hh = 0; hh < 4; ++hh) {
            vfloat4 o;
            o.x = acc[0][hh]; o.y = acc[1][hh]; o.z = acc[2][hh]; o.w = acc[3][hh];
            vfloat4* dstp = (vfloat4*)(out + ((size_t)b * NH + (h0 + hh)) * NT + t0);
            __builtin_nontemporal_store(o, dstp);
        }
    }
}

extern "C" void kernel_launch(void* const* d_in, const int* in_sizes, int n_in,
                              void* d_out, int out_size, void* d_ws, size_t ws_size,
                              hipStream_t stream) {
    const int*   codes = (const int*)d_in[0];    // [Q,B,T] int32
    const float* cb    = (const float*)d_in[1];  // [Q,K,D] f32
    const float* W     = (const float*)d_in[2];  // [Q,H,D] f32
    const float* bias  = (const float*)d_in[3];  // [Q,H] f32
    float*       out   = (float*)d_out;          // [B,H,T] f32
    uint2*       Pt    = (uint2*)d_ws;           // [256 hg][Q][K] uint2 = 16 MB

    build_Pt<<<NQ * 4 * 16, 256, 0, stream>>>(cb, W, bias, Pt);
    gather_sum<<<256 * NB, 512, 0, stream>>>(codes, Pt, out);
}